// Round 4
// baseline (1446.435 us; speedup 1.0000x reference)
//
#include <hip/hip_runtime.h>

#define D_FEAT 128
#define NB_SHIFT 6
#define BUCKET_NODES 64
#define SUBS 8
#define SUBCAP 256               // per sub-bucket capacity (mean 128, std ~11)
#define CAPB (SUBS * SUBCAP)     // 2048 ints per bucket

typedef short bf16x8 __attribute__((ext_vector_type(8)));
typedef float f32x4 __attribute__((ext_vector_type(4)));

__device__ __forceinline__ unsigned short f2bf(float f) {
    unsigned u = __builtin_bit_cast(unsigned, f);
    u += 0x7FFF + ((u >> 16) & 1);   // round-to-nearest-even
    return (unsigned short)(u >> 16);
}

// ws int layout: [flag:64][bcnt:12544][bdata:NBUCK*2048][Wc 16384 ints][xb N*64 ints]

// ---------------- K0: init ----------------
__global__ void init_kernel(int* __restrict__ bcnt, int total, int* __restrict__ flag) {
    int gid = blockIdx.x * blockDim.x + threadIdx.x;
    if (gid == 0) *flag = 1;
    if (gid < total) bcnt[gid] = 0;
}

// ---------------- K1: detect int64 vs int32 edge_index ----------------
__global__ void detect_i64_kernel(const int* __restrict__ ei32, int* __restrict__ flag) {
    int t = threadIdx.x;
    int nonzero = 0;
    for (int i = t; i < 4096; i += 256) {
        if (ei32[2 * i + 1] != 0) nonzero = 1;
    }
    if (nonzero) atomicAnd(flag, 0);
}

__device__ __forceinline__ void decode_edge(const int* ei, int e, int E, int is64,
                                            int& src, int& dst) {
    if (is64) {
        src = ei[2 * e];
        dst = ei[2 * E + 2 * e];
    } else {
        src = ei[e];
        dst = ei[E + e];
    }
}

// ---------------- K2: x -> bf16 ----------------
__global__ void xb_kernel(const float4* __restrict__ x4, uint2* __restrict__ xb2,
                          long total4) {
    long gid = (long)blockIdx.x * blockDim.x + threadIdx.x;
    if (gid >= total4) return;
    float4 v = x4[gid];
    uint2 o;
    o.x = (unsigned)f2bf(v.x) | ((unsigned)f2bf(v.y) << 16);
    o.y = (unsigned)f2bf(v.z) | ((unsigned)f2bf(v.w) << 16);
    xb2[gid] = o;
}

// ---------------- K3: pack [Wl|Wr] -> Wc[n][k] bf16 ----------------
__global__ void wc_kernel(const float* __restrict__ Wl, const float* __restrict__ Wr,
                          unsigned short* __restrict__ Wc) {
    int n = blockIdx.x;
    int k = threadIdx.x;
    float w = (k < 128) ? Wl[n * 128 + k] : Wr[n * 128 + (k - 128)];
    Wc[n * 256 + k] = f2bf(w);
}

// ---------------- K4: binning ----------------
__global__ void bin_kernel(const int* __restrict__ ei, int* __restrict__ bcnt,
                           int* __restrict__ bdata, const int* __restrict__ flag, int E) {
    int e = blockIdx.x * blockDim.x + threadIdx.x;
    if (e >= E) return;
    int is64 = *flag;
    int src, dst;
    decode_edge(ei, e, E, is64, src, dst);
    int b = dst >> NB_SHIFT;
    int sub = blockIdx.x & (SUBS - 1);
    int slot = atomicAdd(&bcnt[b * SUBS + sub], 1);
    if (slot < SUBCAP)
        bdata[(long)b * CAPB + sub * SUBCAP + slot] =
            ((dst & (BUCKET_NODES - 1)) << 17) | src;
}

// ---------------- K5: fused gather + GEMM per bucket ----------------
// Block = 64 nodes. Edge-parallel gather with LDS f32 atomics, then MFMA:
// out[64,128] = [agg_bf16 | xb_rows] (K=256) @ Wc^T + bl
__global__ __launch_bounds__(256) void fused_kernel(
    const unsigned int* __restrict__ xb, const int* __restrict__ bcnt,
    const int* __restrict__ bdata, const unsigned short* __restrict__ Wc,
    const float* __restrict__ bl, float* __restrict__ out, int N) {
    __shared__ float sagg[64 * 132];                      // 33792 B, stride 132 f32
    __shared__ __align__(16) unsigned short A[64 * 264];  // 33792 B, stride 264 bf16
    __shared__ int ldeg[64];
    __shared__ float sinvd[64];
    __shared__ int scnt[SUBS];

    int* raw = (int*)A;  // first 8KB of A reused as edge buffer during gather

    const int t = threadIdx.x;
    const int wv = t >> 6;
    const int lane = t & 63;
    const int b = blockIdx.x;
    const int node0 = b << NB_SHIFT;

    // zero accumulators / degree
    for (int i = t; i < 64 * 132; i += 256) sagg[i] = 0.0f;
    if (t < 64) ldeg[t] = 0;
    if (t < SUBS) scnt[t] = min(bcnt[b * SUBS + t], SUBCAP);
    __syncthreads();

    // load bucket edges into LDS (segmented, coalesced)
    for (int idx = t; idx < CAPB; idx += 256) {
        int s = idx >> 8;  // SUBCAP = 256
        int i = idx & (SUBCAP - 1);
        if (i < scnt[s]) raw[idx] = bdata[(long)b * CAPB + idx];
    }
    __syncthreads();

    // edge-parallel gather: wave w handles sub-segments w and w+4
    for (int s = wv; s < SUBS; s += 4) {
        int cs = scnt[s];
#pragma unroll 4
        for (int i = 0; i < cs; ++i) {
            int packed = raw[s * SUBCAP + i];  // LDS broadcast
            int src = packed & 0x1FFFF;
            int ld = packed >> 17;
            unsigned v = xb[(long)src * 64 + lane];
            float lo = __builtin_bit_cast(float, v << 16);
            float hi = __builtin_bit_cast(float, v & 0xFFFF0000u);
            atomicAdd(&sagg[ld * 132 + 2 * lane], lo);
            atomicAdd(&sagg[ld * 132 + 2 * lane + 1], hi);
            if (lane == 0) atomicAdd(&ldeg[ld], 1);
        }
    }
    __syncthreads();

    if (t < 64) sinvd[t] = 1.0f / (float)max(ldeg[t], 1);
    __syncthreads();

    // agg -> A[:, 0:128] bf16 (mean fused); overwrites raw region (done with it)
    for (int idx = t; idx < 64 * 64; idx += 256) {
        int row = idx >> 6;
        int cp = idx & 63;
        float iv = sinvd[row];
        unsigned lo16 = f2bf(sagg[row * 132 + 2 * cp] * iv);
        unsigned hi16 = f2bf(sagg[row * 132 + 2 * cp + 1] * iv);
        *(unsigned*)&A[row * 264 + 2 * cp] = lo16 | (hi16 << 16);
    }
    // own xb rows -> A[:, 128:256]
    for (int idx = t; idx < 64 * 16; idx += 256) {
        int row = idx >> 4;
        int g = idx & 15;
        int node = node0 + row;
        uint4 val = make_uint4(0u, 0u, 0u, 0u);
        if (node < N) val = ((const uint4*)xb)[(long)node * 16 + g];
        *(uint4*)&A[row * 264 + 128 + g * 8] = val;
    }
    __syncthreads();

    // MFMA: wave w owns rows [w*16, w*16+16), all 128 cols
    const int l15 = lane & 15;
    const int quad = lane >> 4;
    f32x4 acc[8];
#pragma unroll
    for (int nt = 0; nt < 8; ++nt) acc[nt] = (f32x4){0.f, 0.f, 0.f, 0.f};

#pragma unroll
    for (int kc = 0; kc < 8; ++kc) {
        const int k0 = kc * 32;
        bf16x8 afrag = *(const bf16x8*)&A[(wv * 16 + l15) * 264 + k0 + quad * 8];
#pragma unroll
        for (int nt = 0; nt < 8; ++nt) {
            bf16x8 bfrag = *(const bf16x8*)&Wc[(nt * 16 + l15) * 256 + k0 + quad * 8];
            acc[nt] = __builtin_amdgcn_mfma_f32_16x16x32_bf16(afrag, bfrag, acc[nt], 0, 0, 0);
        }
    }

    // epilogue: C/D layout col=lane&15, row=quad*4+reg
#pragma unroll
    for (int nt = 0; nt < 8; ++nt) {
        int col = nt * 16 + l15;
        float bias = bl[col];
#pragma unroll
        for (int r = 0; r < 4; ++r) {
            int node = node0 + wv * 16 + quad * 4 + r;
            if (node < N) out[(long)node * 128 + col] = acc[nt][r] + bias;
        }
    }
}

extern "C" void kernel_launch(void* const* d_in, const int* in_sizes, int n_in,
                              void* d_out, int out_size, void* d_ws, size_t ws_size,
                              hipStream_t stream) {
    const float* x = (const float*)d_in[0];
    const int* ei = (const int*)d_in[1];
    const float* Wl = (const float*)d_in[2];
    const float* bl = (const float*)d_in[3];
    const float* Wr = (const float*)d_in[4];
    float* out = (float*)d_out;

    const int N = in_sizes[0] / D_FEAT;  // 100000
    const int E = in_sizes[1] / 2;       // 1600000
    const int NBUCK = (N + BUCKET_NODES - 1) >> NB_SHIFT;  // 1563

    int* wsI = (int*)d_ws;
    int* flag = wsI;                   // 64
    int* bcnt = flag + 64;             // 12544 (NBUCK*8 = 12504, padded)
    int* bdata = bcnt + 12544;         // NBUCK * 2048 ints
    unsigned short* Wc = (unsigned short*)(bdata + (long)NBUCK * CAPB);  // 64KB
    unsigned int* xb = (unsigned int*)(Wc + 128 * 256);                  // N*64 uints

    init_kernel<<<(NBUCK * SUBS + 255) / 256, 256, 0, stream>>>(bcnt, NBUCK * SUBS, flag);
    detect_i64_kernel<<<1, 256, 0, stream>>>(ei, flag);
    xb_kernel<<<(int)(((long)N * 32 + 255) / 256), 256, 0, stream>>>(
        (const float4*)x, (uint2*)xb, (long)N * 32);
    wc_kernel<<<128, 256, 0, stream>>>(Wl, Wr, Wc);
    bin_kernel<<<(E + 255) / 256, 256, 0, stream>>>(ei, bcnt, bdata, flag, E);
    fused_kernel<<<NBUCK, 256, 0, stream>>>(xb, bcnt, bdata, Wc, bl, out, N);
}

// Round 5
// 498.438 us; speedup vs baseline: 2.9019x; 2.9019x over previous
//
#include <hip/hip_runtime.h>

#define D_FEAT 128
#define SUBS 8

typedef short bf16x8 __attribute__((ext_vector_type(8)));
typedef float f32x4 __attribute__((ext_vector_type(4)));

__device__ __forceinline__ unsigned short f2bf(float f) {
    unsigned u = __builtin_bit_cast(unsigned, f);
    u += 0x7FFF + ((u >> 16) & 1);   // round-to-nearest-even
    return (unsigned short)(u >> 16);
}

// ws int layout: [flag:64][scnt:8N (becomes cursor)][offsets:8N+1 pad][partials:4096][adj:E]
// then Wc[128*256] bf16, xb[N*64] uint (bf16x2)

// ---------------- K0: init ----------------
__global__ void init_kernel(int* __restrict__ scnt, long total, int* __restrict__ flag) {
    long gid = (long)blockIdx.x * blockDim.x + threadIdx.x;
    if (gid == 0) *flag = 1;
    if (gid < total) scnt[gid] = 0;
}

// ---------------- K1: detect int64 vs int32 edge_index ----------------
__global__ void detect_i64_kernel(const int* __restrict__ ei32, int* __restrict__ flag) {
    int t = threadIdx.x;
    int nonzero = 0;
    for (int i = t; i < 4096; i += 256) {
        if (ei32[2 * i + 1] != 0) nonzero = 1;
    }
    if (nonzero) atomicAnd(flag, 0);
}

__device__ __forceinline__ void decode_edge(const int* ei, int e, int E, int is64,
                                            int& src, int& dst) {
    if (is64) {
        src = ei[2 * e];
        dst = ei[2 * E + 2 * e];
    } else {
        src = ei[e];
        dst = ei[E + e];
    }
}

// ---------------- K2: x -> bf16 ----------------
__global__ void xb_kernel(const float4* __restrict__ x4, uint2* __restrict__ xb2,
                          long total4) {
    long gid = (long)blockIdx.x * blockDim.x + threadIdx.x;
    if (gid >= total4) return;
    float4 v = x4[gid];
    uint2 o;
    o.x = (unsigned)f2bf(v.x) | ((unsigned)f2bf(v.y) << 16);
    o.y = (unsigned)f2bf(v.z) | ((unsigned)f2bf(v.w) << 16);
    xb2[gid] = o;
}

// ---------------- K3: pack [Wl|Wr] -> Wc[n][k] bf16 ----------------
__global__ void wc_kernel(const float* __restrict__ Wl, const float* __restrict__ Wr,
                          unsigned short* __restrict__ Wc) {
    int n = blockIdx.x;
    int k = threadIdx.x;
    float w = (k < 128) ? Wl[n * 128 + k] : Wr[n * 128 + (k - 128)];
    Wc[n * 256 + k] = f2bf(w);
}

// ---------------- K4: degree count, XCD-sliced (s = blockIdx&7) ----------------
__global__ void count_kernel(const int* __restrict__ ei, int* __restrict__ scnt,
                             const int* __restrict__ flag, int E, int N) {
    int e = blockIdx.x * blockDim.x + threadIdx.x;
    if (e >= E) return;
    int is64 = *flag;
    int src, dst;
    decode_edge(ei, e, E, is64, src, dst);
    int s = blockIdx.x & (SUBS - 1);
    atomicAdd(&scnt[(long)s * N + dst], 1);
}

// ---------------- K5a: block-local exclusive scan over 8N ----------------
__global__ __launch_bounds__(256) void scan1_kernel(const int* __restrict__ scnt,
                                                    int* __restrict__ offsets,
                                                    int* __restrict__ partials, long total) {
    __shared__ int s[256];
    int t = threadIdx.x;
    long gid = (long)blockIdx.x * 256 + t;
    int v = (gid < total) ? scnt[gid] : 0;
    s[t] = v;
    __syncthreads();
    for (int off = 1; off < 256; off <<= 1) {
        int add = (t >= off) ? s[t - off] : 0;
        __syncthreads();
        s[t] += add;
        __syncthreads();
    }
    if (gid < total) offsets[gid] = s[t] - v;
    if (t == 255) partials[blockIdx.x] = s[255];
}

// ---------------- K5b: serial-chunk scan of partials (1 block) ----------------
__global__ __launch_bounds__(256) void scan2_kernel(int* __restrict__ partials, int P,
                                                    int* __restrict__ offsets,
                                                    long total, int E) {
    __shared__ int s[256];
    int t = threadIdx.x;
    int run = 0;
    for (int base = 0; base < P; base += 256) {
        int v = (base + t < P) ? partials[base + t] : 0;
        s[t] = v;
        __syncthreads();
        for (int off = 1; off < 256; off <<= 1) {
            int add = (t >= off) ? s[t - off] : 0;
            __syncthreads();
            s[t] += add;
            __syncthreads();
        }
        if (base + t < P) partials[base + t] = s[t] - v + run;
        run += s[255];
        __syncthreads();
    }
    if (t == 0) offsets[total] = E;
}

// ---------------- K5c: finalize offsets, init cursor (reuses scnt) ----------------
__global__ void scan3_kernel(int* __restrict__ offsets, const int* __restrict__ partials,
                             int* __restrict__ cursor, long total) {
    long gid = (long)blockIdx.x * blockDim.x + threadIdx.x;
    if (gid >= total) return;
    int o = offsets[gid] + partials[blockIdx.x];
    offsets[gid] = o;
    cursor[gid] = o;
}

// ---------------- K6: fill adjacency, XCD-sliced ----------------
__global__ void fill_kernel(const int* __restrict__ ei, int* __restrict__ cursor,
                            int* __restrict__ adj, const int* __restrict__ flag,
                            int E, int N) {
    int e = blockIdx.x * blockDim.x + threadIdx.x;
    if (e >= E) return;
    int is64 = *flag;
    int src, dst;
    decode_edge(ei, e, E, is64, src, dst);
    int s = blockIdx.x & (SUBS - 1);
    int slot = atomicAdd(&cursor[(long)s * N + dst], 1);
    adj[slot] = src;
}

// ---------------- K7: fused gather + MFMA GEMM, 16 nodes per block ----------------
// Phase 1: wave w gathers nodes w*4..w*4+3 (lane owns cols 2l,2l+1), mean -> bf16
//          into A[16][264]; own xb row -> A[:,128:256].
// Phase 2: 16x128 tile: wave w computes cols [w*32,w*32+32), 2 n-tiles x 8 kc.
__global__ __launch_bounds__(256) void gg_kernel(
    const unsigned int* __restrict__ xb, const int* __restrict__ offsets,
    const int* __restrict__ adj, const unsigned short* __restrict__ Wc,
    const float* __restrict__ bl, float* __restrict__ out, int N) {
    __shared__ __align__(16) unsigned short A[16 * 264];

    const int t = threadIdx.x;
    const int wv = t >> 6;
    const int lane = t & 63;
    const int n0 = blockIdx.x * 16;

    // phase 1: gather
#pragma unroll
    for (int q = 0; q < 4; ++q) {
        int r = wv * 4 + q;
        int n = n0 + r;
        float a0 = 0.0f, a1 = 0.0f;
        int deg = 0;
        unsigned xv = 0;
        if (n < N) {
            xv = xb[(long)n * 64 + lane];
#pragma unroll
            for (int s = 0; s < SUBS; ++s) {
                int st = offsets[(long)s * N + n];
                int en = offsets[(long)s * N + n + 1];
                deg += en - st;
                for (int j = st; j < en; ++j) {
                    int src = adj[j];
                    unsigned v = xb[(long)src * 64 + lane];
                    a0 += __builtin_bit_cast(float, v << 16);
                    a1 += __builtin_bit_cast(float, v & 0xFFFF0000u);
                }
            }
        }
        float iv = 1.0f / (float)max(deg, 1);
        unsigned lo = f2bf(a0 * iv);
        unsigned hi = f2bf(a1 * iv);
        *(unsigned*)&A[r * 264 + 2 * lane] = lo | (hi << 16);
        *(unsigned*)&A[r * 264 + 128 + 2 * lane] = xv;
    }
    __syncthreads();

    // phase 2: MFMA
    const int l15 = lane & 15;
    const int quad = lane >> 4;
    f32x4 acc[2];
    acc[0] = (f32x4){0.f, 0.f, 0.f, 0.f};
    acc[1] = (f32x4){0.f, 0.f, 0.f, 0.f};

#pragma unroll
    for (int kc = 0; kc < 8; ++kc) {
        const int k0 = kc * 32;
        bf16x8 af = *(const bf16x8*)&A[l15 * 264 + k0 + quad * 8];
#pragma unroll
        for (int nt = 0; nt < 2; ++nt) {
            int col = wv * 32 + nt * 16 + l15;
            bf16x8 bf = *(const bf16x8*)&Wc[col * 256 + k0 + quad * 8];
            acc[nt] = __builtin_amdgcn_mfma_f32_16x16x32_bf16(af, bf, acc[nt], 0, 0, 0);
        }
    }

    // epilogue: C/D layout col=lane&15, row=quad*4+reg
#pragma unroll
    for (int nt = 0; nt < 2; ++nt) {
        int col = wv * 32 + nt * 16 + l15;
        float bias = bl[col];
#pragma unroll
        for (int r = 0; r < 4; ++r) {
            int node = n0 + quad * 4 + r;
            if (node < N) out[(long)node * 128 + col] = acc[nt][r] + bias;
        }
    }
}

extern "C" void kernel_launch(void* const* d_in, const int* in_sizes, int n_in,
                              void* d_out, int out_size, void* d_ws, size_t ws_size,
                              hipStream_t stream) {
    const float* x = (const float*)d_in[0];
    const int* ei = (const int*)d_in[1];
    const float* Wl = (const float*)d_in[2];
    const float* bl = (const float*)d_in[3];
    const float* Wr = (const float*)d_in[4];
    float* out = (float*)d_out;

    const int N = in_sizes[0] / D_FEAT;  // 100000
    const int E = in_sizes[1] / 2;       // 1600000
    const long SUBN = (long)SUBS * N;    // 800000

    int* wsI = (int*)d_ws;
    int* flag = wsI;                       // 64
    int* scnt = flag + 64;                 // 8N (doubles as cursor)
    int* offsets = scnt + SUBN;            // 8N+1 (+pad to 64)
    int* partials = offsets + SUBN + 64;   // 4096
    int* adj = partials + 4096;            // E
    unsigned short* Wc = (unsigned short*)(adj + E);        // 64KB
    unsigned int* xb = (unsigned int*)(Wc + 128 * 256);     // N*64 uints

    const int P = (int)((SUBN + 255) / 256);  // 3125

    init_kernel<<<P, 256, 0, stream>>>(scnt, SUBN, flag);
    detect_i64_kernel<<<1, 256, 0, stream>>>(ei, flag);
    xb_kernel<<<(int)(((long)N * 32 + 255) / 256), 256, 0, stream>>>(
        (const float4*)x, (uint2*)xb, (long)N * 32);
    wc_kernel<<<128, 256, 0, stream>>>(Wl, Wr, Wc);
    count_kernel<<<(E + 255) / 256, 256, 0, stream>>>(ei, scnt, flag, E, N);
    scan1_kernel<<<P, 256, 0, stream>>>(scnt, offsets, partials, SUBN);
    scan2_kernel<<<1, 256, 0, stream>>>(partials, P, offsets, SUBN, E);
    scan3_kernel<<<P, 256, 0, stream>>>(offsets, partials, scnt, SUBN);
    fill_kernel<<<(E + 255) / 256, 256, 0, stream>>>(ei, scnt, adj, flag, E, N);
    gg_kernel<<<(N + 15) / 16, 256, 0, stream>>>(xb, offsets, adj, Wc, bl, out, N);
}

// Round 6
// 423.123 us; speedup vs baseline: 3.4185x; 1.1780x over previous
//
#include <hip/hip_runtime.h>

#define D_FEAT 128
#define SUBS 8

typedef short bf16x8 __attribute__((ext_vector_type(8)));
typedef float f32x4 __attribute__((ext_vector_type(4)));

__device__ __forceinline__ unsigned short f2bf(float f) {
    unsigned u = __builtin_bit_cast(unsigned, f);
    u += 0x7FFF + ((u >> 16) & 1);   // round-to-nearest-even
    return (unsigned short)(u >> 16);
}

// ws int layout: [flag:64][scnt:8N (becomes cursor)][offsets:8N+1 pad][partials:4096][adj:E]
// then Wc[128*256] bf16, xb[N*64] uint (bf16x2)

// ---------------- K0: init ----------------
__global__ void init_kernel(int* __restrict__ scnt, long total, int* __restrict__ flag) {
    long gid = (long)blockIdx.x * blockDim.x + threadIdx.x;
    if (gid == 0) *flag = 1;
    if (gid < total) scnt[gid] = 0;
}

// ---------------- K1: detect int64 vs int32 edge_index ----------------
__global__ void detect_i64_kernel(const int* __restrict__ ei32, int* __restrict__ flag) {
    int t = threadIdx.x;
    int nonzero = 0;
    for (int i = t; i < 4096; i += 256) {
        if (ei32[2 * i + 1] != 0) nonzero = 1;
    }
    if (nonzero) atomicAnd(flag, 0);
}

__device__ __forceinline__ void decode_edge(const int* ei, int e, int E, int is64,
                                            int& src, int& dst) {
    if (is64) {
        src = ei[2 * e];
        dst = ei[2 * E + 2 * e];
    } else {
        src = ei[e];
        dst = ei[E + e];
    }
}

// ---------------- K2: x -> bf16 ----------------
__global__ void xb_kernel(const float4* __restrict__ x4, uint2* __restrict__ xb2,
                          long total4) {
    long gid = (long)blockIdx.x * blockDim.x + threadIdx.x;
    if (gid >= total4) return;
    float4 v = x4[gid];
    uint2 o;
    o.x = (unsigned)f2bf(v.x) | ((unsigned)f2bf(v.y) << 16);
    o.y = (unsigned)f2bf(v.z) | ((unsigned)f2bf(v.w) << 16);
    xb2[gid] = o;
}

// ---------------- K3: pack [Wl|Wr] -> Wc[n][k] bf16 ----------------
__global__ void wc_kernel(const float* __restrict__ Wl, const float* __restrict__ Wr,
                          unsigned short* __restrict__ Wc) {
    int n = blockIdx.x;
    int k = threadIdx.x;
    float w = (k < 128) ? Wl[n * 128 + k] : Wr[n * 128 + (k - 128)];
    Wc[n * 256 + k] = f2bf(w);
}

// ---------------- K4: degree count, XCD-sliced (s = blockIdx&7) ----------------
__global__ void count_kernel(const int* __restrict__ ei, int* __restrict__ scnt,
                             const int* __restrict__ flag, int E, int N) {
    int e = blockIdx.x * blockDim.x + threadIdx.x;
    if (e >= E) return;
    int is64 = *flag;
    int src, dst;
    decode_edge(ei, e, E, is64, src, dst);
    int s = blockIdx.x & (SUBS - 1);
    atomicAdd(&scnt[(long)s * N + dst], 1);
}

// ---------------- K5a: block-local exclusive scan over 8N ----------------
__global__ __launch_bounds__(256) void scan1_kernel(const int* __restrict__ scnt,
                                                    int* __restrict__ offsets,
                                                    int* __restrict__ partials, long total) {
    __shared__ int s[256];
    int t = threadIdx.x;
    long gid = (long)blockIdx.x * 256 + t;
    int v = (gid < total) ? scnt[gid] : 0;
    s[t] = v;
    __syncthreads();
    for (int off = 1; off < 256; off <<= 1) {
        int add = (t >= off) ? s[t - off] : 0;
        __syncthreads();
        s[t] += add;
        __syncthreads();
    }
    if (gid < total) offsets[gid] = s[t] - v;
    if (t == 255) partials[blockIdx.x] = s[255];
}

// ---------------- K5b: serial-chunk scan of partials (1 block) ----------------
__global__ __launch_bounds__(256) void scan2_kernel(int* __restrict__ partials, int P,
                                                    int* __restrict__ offsets,
                                                    long total, int E) {
    __shared__ int s[256];
    int t = threadIdx.x;
    int run = 0;
    for (int base = 0; base < P; base += 256) {
        int v = (base + t < P) ? partials[base + t] : 0;
        s[t] = v;
        __syncthreads();
        for (int off = 1; off < 256; off <<= 1) {
            int add = (t >= off) ? s[t - off] : 0;
            __syncthreads();
            s[t] += add;
            __syncthreads();
        }
        if (base + t < P) partials[base + t] = s[t] - v + run;
        run += s[255];
        __syncthreads();
    }
    if (t == 0) offsets[total] = E;
}

// ---------------- K5c: finalize offsets, init cursor (reuses scnt) ----------------
__global__ void scan3_kernel(int* __restrict__ offsets, const int* __restrict__ partials,
                             int* __restrict__ cursor, long total) {
    long gid = (long)blockIdx.x * blockDim.x + threadIdx.x;
    if (gid >= total) return;
    int o = offsets[gid] + partials[blockIdx.x];
    offsets[gid] = o;
    cursor[gid] = o;
}

// ---------------- K6: fill adjacency, XCD-sliced ----------------
__global__ void fill_kernel(const int* __restrict__ ei, int* __restrict__ cursor,
                            int* __restrict__ adj, const int* __restrict__ flag,
                            int E, int N) {
    int e = blockIdx.x * blockDim.x + threadIdx.x;
    if (e >= E) return;
    int is64 = *flag;
    int src, dst;
    decode_edge(ei, e, E, is64, src, dst);
    int s = blockIdx.x & (SUBS - 1);
    int slot = atomicAdd(&cursor[(long)s * N + dst], 1);
    adj[slot] = src;
}

// ---------------- K7: fused gather + MFMA GEMM, 16 nodes per block ----------------
// Gather, per node (wave-collective, high MLP):
//   1. lanes 0-15 fetch the 16 segment offsets in one load
//   2. lane i maps itself to edge i via uniform prefix over the 8 segments,
//      loads its adj entry (one load for <=64 edges)
//   3. xb-row loads issue back-to-back (shfl-broadcast src), no chases between
__global__ __launch_bounds__(256) void gg_kernel(
    const unsigned int* __restrict__ xb, const int* __restrict__ offsets,
    const int* __restrict__ adj, const unsigned short* __restrict__ Wc,
    const float* __restrict__ bl, float* __restrict__ out, int N) {
    __shared__ __align__(16) unsigned short A[16 * 264];

    const int t = threadIdx.x;
    const int wv = t >> 6;
    const int lane = t & 63;
    const int n0 = blockIdx.x * 16;

    // phase 1: gather (wave w handles rows w*4..w*4+3)
    for (int q = 0; q < 4; ++q) {
        int r = wv * 4 + q;
        int n = n0 + r;
        float a0 = 0.0f, a1 = 0.0f;
        unsigned xv = 0;
        int deg = 0;
        if (n < N) {
            xv = xb[(long)n * 64 + lane];
            int o = 0;
            if (lane < 16) {
                int s = lane & 7;
                o = offsets[(long)s * N + n + (lane >> 3)];
            }
            int st_s[8], len_s[8];
#pragma unroll
            for (int s = 0; s < 8; ++s) {
                int sts = __shfl(o, s);
                int ens = __shfl(o, s + 8);
                st_s[s] = sts;
                len_s[s] = ens - sts;
                deg += len_s[s];
            }
            for (int base = 0; base < deg; base += 64) {
                int i = base + lane;
                int gidx = -1;
                int cum = 0;
#pragma unroll
                for (int s = 0; s < 8; ++s) {
                    if (i >= cum && i < cum + len_s[s]) gidx = st_s[s] + (i - cum);
                    cum += len_s[s];
                }
                int adjv = (gidx >= 0) ? adj[gidx] : 0;
                int cnt = min(64, deg - base);
                for (int tt = 0; tt < cnt; ++tt) {
                    int src = __shfl(adjv, tt);
                    unsigned v = xb[(long)src * 64 + lane];
                    a0 += __builtin_bit_cast(float, v << 16);
                    a1 += __builtin_bit_cast(float, v & 0xFFFF0000u);
                }
            }
        }
        float iv = 1.0f / (float)max(deg, 1);
        unsigned lo = f2bf(a0 * iv);
        unsigned hi = f2bf(a1 * iv);
        *(unsigned*)&A[r * 264 + 2 * lane] = lo | (hi << 16);
        *(unsigned*)&A[r * 264 + 128 + 2 * lane] = xv;
    }
    __syncthreads();

    // phase 2: MFMA — wave w computes cols [w*32, w*32+32)
    const int l15 = lane & 15;
    const int quad = lane >> 4;
    f32x4 acc[2];
    acc[0] = (f32x4){0.f, 0.f, 0.f, 0.f};
    acc[1] = (f32x4){0.f, 0.f, 0.f, 0.f};

#pragma unroll
    for (int kc = 0; kc < 8; ++kc) {
        const int k0 = kc * 32;
        bf16x8 af = *(const bf16x8*)&A[l15 * 264 + k0 + quad * 8];
#pragma unroll
        for (int nt = 0; nt < 2; ++nt) {
            int col = wv * 32 + nt * 16 + l15;
            bf16x8 bf = *(const bf16x8*)&Wc[col * 256 + k0 + quad * 8];
            acc[nt] = __builtin_amdgcn_mfma_f32_16x16x32_bf16(af, bf, acc[nt], 0, 0, 0);
        }
    }

    // epilogue: C/D layout col=lane&15, row=quad*4+reg
#pragma unroll
    for (int nt = 0; nt < 2; ++nt) {
        int col = wv * 32 + nt * 16 + l15;
        float bias = bl[col];
#pragma unroll
        for (int r = 0; r < 4; ++r) {
            int node = n0 + quad * 4 + r;
            if (node < N) out[(long)node * 128 + col] = acc[nt][r] + bias;
        }
    }
}

extern "C" void kernel_launch(void* const* d_in, const int* in_sizes, int n_in,
                              void* d_out, int out_size, void* d_ws, size_t ws_size,
                              hipStream_t stream) {
    const float* x = (const float*)d_in[0];
    const int* ei = (const int*)d_in[1];
    const float* Wl = (const float*)d_in[2];
    const float* bl = (const float*)d_in[3];
    const float* Wr = (const float*)d_in[4];
    float* out = (float*)d_out;

    const int N = in_sizes[0] / D_FEAT;  // 100000
    const int E = in_sizes[1] / 2;       // 1600000
    const long SUBN = (long)SUBS * N;    // 800000

    int* wsI = (int*)d_ws;
    int* flag = wsI;                       // 64
    int* scnt = flag + 64;                 // 8N (doubles as cursor)
    int* offsets = scnt + SUBN;            // 8N+1 (+pad to 64)
    int* partials = offsets + SUBN + 64;   // 4096
    int* adj = partials + 4096;            // E
    unsigned short* Wc = (unsigned short*)(adj + E);        // 64KB
    unsigned int* xb = (unsigned int*)(Wc + 128 * 256);     // N*64 uints

    const int P = (int)((SUBN + 255) / 256);  // 3125

    init_kernel<<<P, 256, 0, stream>>>(scnt, SUBN, flag);
    detect_i64_kernel<<<1, 256, 0, stream>>>(ei, flag);
    xb_kernel<<<(int)(((long)N * 32 + 255) / 256), 256, 0, stream>>>(
        (const float4*)x, (uint2*)xb, (long)N * 32);
    wc_kernel<<<128, 256, 0, stream>>>(Wl, Wr, Wc);
    count_kernel<<<(E + 255) / 256, 256, 0, stream>>>(ei, scnt, flag, E, N);
    scan1_kernel<<<P, 256, 0, stream>>>(scnt, offsets, partials, SUBN);
    scan2_kernel<<<1, 256, 0, stream>>>(partials, P, offsets, SUBN, E);
    scan3_kernel<<<P, 256, 0, stream>>>(offsets, partials, scnt, SUBN);
    fill_kernel<<<(E + 255) / 256, 256, 0, stream>>>(ei, scnt, adj, flag, E, N);
    gg_kernel<<<(N + 15) / 16, 256, 0, stream>>>(xb, offsets, adj, Wc, bl, out, N);
}